// Round 3
// baseline (217.292 us; speedup 1.0000x reference)
//
#include <hip/hip_runtime.h>

// msg[e] = src_emb[src_idx[e]] * e_att[e]; out = segment_sum(msg, dst_idx, N_DST)
// src_emb [50000,64] f32, e_att [800000,1] f32, src_idx/dst_idx [800000] i32,
// out [50000,64] f32.
//
// CSR two-phase, payload variant: counts -> scan -> scatter (src,att) 8B
// payload into dst-sorted order -> atomic-free gather-sum (one wave per dst
// row, streaming payload + contiguous 256B src_emb row reads).

#define D 64

// ---------------- CSR build ----------------

__global__ void __launch_bounds__(256)
hist_kernel(const int* __restrict__ dst_idx, int* __restrict__ counts, int E) {
    int e = blockIdx.x * blockDim.x + threadIdx.x;
    if (e < E) atomicAdd(&counts[dst_idx[e]], 1);
}

// Single block: thread t sums counts[t*256 .. t*256+255], then exclusive-scans
// the 256 partials -> blocksums[t] (t < nb). Replaces block_reduce + scan_bs.
__global__ void __launch_bounds__(256)
reduce_scan_kernel(const int* __restrict__ counts, int* __restrict__ blocksums,
                   int n, int nb) {
    __shared__ int lds[256];
    int t = threadIdx.x;
    int sum = 0;
    int base = t * 256;
    if (t < nb) {
        int lim = min(base + 256, n);
        for (int i = base; i < lim; ++i) sum += counts[i];
    }
    lds[t] = sum;
    __syncthreads();
    for (int off = 1; off < 256; off <<= 1) {
        int x = (t >= off) ? lds[t - off] : 0;
        __syncthreads();
        lds[t] += x;
        __syncthreads();
    }
    if (t < nb) blocksums[t] = lds[t] - sum;   // exclusive
}

__global__ void __launch_bounds__(256)
scan_final_kernel(const int* __restrict__ counts, const int* __restrict__ blocksums,
                  int* __restrict__ offsets, int* __restrict__ cursor, int n) {
    __shared__ int lds[256];
    int t = threadIdx.x;
    int i = blockIdx.x * 256 + t;
    int v = (i < n) ? counts[i] : 0;
    lds[t] = v;
    __syncthreads();
    for (int off = 1; off < 256; off <<= 1) {
        int x = (t >= off) ? lds[t - off] : 0;
        __syncthreads();
        lds[t] += x;
        __syncthreads();
    }
    int excl = lds[t] - v + blocksums[blockIdx.x];
    if (i < n) {
        offsets[i] = excl;
        cursor[i]  = excl;
        if (i == n - 1) offsets[n] = excl + v;   // sentinel: offsets[n_dst] = E
    }
}

// Scatter packed (src, att) payload into dst-sorted order. 8B nontemporal
// store: payload is streamed exactly once by gather, no reuse.
__global__ void __launch_bounds__(256)
scatter_payload_kernel(const int* __restrict__ dst_idx, const int* __restrict__ src_idx,
                       const float* __restrict__ e_att, int* __restrict__ cursor,
                       long long* __restrict__ payload, int E) {
    int e = blockIdx.x * blockDim.x + threadIdx.x;
    if (e < E) {
        int d = dst_idx[e];
        int p = atomicAdd(&cursor[d], 1);
        long long pl = ((long long)__float_as_int(e_att[e]) << 32) |
                       (unsigned int)src_idx[e];
        __builtin_nontemporal_store(pl, payload + p);
    }
}

// ---------------- gather-sum ----------------
// One wave per dst row. lane = sub*16 + part: sub (0..3) strides edges,
// part (0..15) owns one float4 of the 64-float row.
__global__ void __launch_bounds__(256)
gather_kernel(const float* __restrict__ src_emb,
              const long long* __restrict__ payload,
              const int* __restrict__ offsets,
              float* __restrict__ out, int n_dst) {
    int w = (blockIdx.x * blockDim.x + threadIdx.x) >> 6;
    if (w >= n_dst) return;
    int lane = threadIdx.x & 63;
    int part = lane & 15;
    int sub  = lane >> 4;

    int start = offsets[w];
    int end   = offsets[w + 1];

    float4 acc = make_float4(0.f, 0.f, 0.f, 0.f);
    for (int p = start + sub; p < end; p += 4) {
        long long pl = payload[p];               // broadcast across 16 lanes
        int   s = (int)(pl & 0xffffffff);
        float a = __int_as_float((int)(pl >> 32));
        float4 v = ((const float4*)src_emb)[(size_t)s * 16 + part];
        acc.x = fmaf(v.x, a, acc.x);
        acc.y = fmaf(v.y, a, acc.y);
        acc.z = fmaf(v.z, a, acc.z);
        acc.w = fmaf(v.w, a, acc.w);
    }
    // combine 4 sub-groups: + lane+32, then + lane+16
    acc.x += __shfl_down(acc.x, 32); acc.y += __shfl_down(acc.y, 32);
    acc.z += __shfl_down(acc.z, 32); acc.w += __shfl_down(acc.w, 32);
    acc.x += __shfl_down(acc.x, 16); acc.y += __shfl_down(acc.y, 16);
    acc.z += __shfl_down(acc.z, 16); acc.w += __shfl_down(acc.w, 16);

    if (sub == 0) ((float4*)out)[(size_t)w * 16 + part] = acc;
}

// ---------------- fallback (ws too small): R1 atomic version ----------------
__global__ void __launch_bounds__(256)
atomic_fallback_kernel(const float* __restrict__ src_emb, const float* __restrict__ e_att,
                       const int* __restrict__ src_idx, const int* __restrict__ dst_idx,
                       float* __restrict__ out, int E) {
    int tid  = blockIdx.x * blockDim.x + threadIdx.x;
    int e    = tid >> 4;
    int part = tid & 15;
    if (e >= E) return;
    int   s = src_idx[e];
    int   d = dst_idx[e];
    float a = e_att[e];
    float4 v = ((const float4*)src_emb)[(size_t)s * 16 + part];
    float* orow = out + (size_t)d * D + part * 4;
    atomicAdd(orow + 0, v.x * a);
    atomicAdd(orow + 1, v.y * a);
    atomicAdd(orow + 2, v.z * a);
    atomicAdd(orow + 3, v.w * a);
}

extern "C" void kernel_launch(void* const* d_in, const int* in_sizes, int n_in,
                              void* d_out, int out_size, void* d_ws, size_t ws_size,
                              hipStream_t stream) {
    const float* src_emb = (const float*)d_in[0];
    const float* e_att   = (const float*)d_in[1];
    const int*   src_idx = (const int*)d_in[2];
    const int*   dst_idx = (const int*)d_in[3];
    float*       out     = (float*)d_out;

    const int E     = in_sizes[2];       // 800000
    const int n_dst = out_size / D;      // 50000

    // ws layout (ints): counts[n] | offsets[n+1] | cursor[n] | blocksums[256] |
    //                   (8B-aligned) payload[E] (long long)
    size_t pidx = (size_t)(3 * n_dst + 1 + 256);
    pidx = (pidx + 1) & ~(size_t)1;                    // 8B-align payload
    size_t need = (pidx + 2ull * E) * sizeof(int);

    if (ws_size < need) {
        hipMemsetAsync(d_out, 0, (size_t)out_size * sizeof(float), stream);
        int total = E * 16;
        atomic_fallback_kernel<<<(total + 255) / 256, 256, 0, stream>>>(
            src_emb, e_att, src_idx, dst_idx, out, E);
        return;
    }

    int* ws        = (int*)d_ws;
    int* counts    = ws;
    int* offsets   = ws + n_dst;                 // n_dst+1 entries
    int* cursor    = ws + 2 * n_dst + 1;
    int* blocksums = ws + 3 * n_dst + 1;
    long long* payload = (long long*)(ws + pidx);

    hipMemsetAsync(counts, 0, (size_t)n_dst * sizeof(int), stream);

    const int nb = (n_dst + 255) / 256;          // 196 (<= 256 required)
    const int eb = (E + 255) / 256;

    hist_kernel<<<eb, 256, 0, stream>>>(dst_idx, counts, E);
    reduce_scan_kernel<<<1, 256, 0, stream>>>(counts, blocksums, n_dst, nb);
    scan_final_kernel<<<nb, 256, 0, stream>>>(counts, blocksums, offsets, cursor, n_dst);
    scatter_payload_kernel<<<eb, 256, 0, stream>>>(dst_idx, src_idx, e_att, cursor,
                                                   payload, E);
    gather_kernel<<<(n_dst + 3) / 4, 256, 0, stream>>>(src_emb, payload, offsets,
                                                       out, n_dst);
}

// Round 4
// 166.941 us; speedup vs baseline: 1.3016x; 1.3016x over previous
//
#include <hip/hip_runtime.h>

// msg[e] = src_emb[src_idx[e]] * e_att[e]; out = segment_sum(msg, dst_idx, N_DST)
// src_emb [50000,64] f32, e_att [800000,1] f32, src_idx/dst_idx [800000] i32,
// out [50000,64] f32.
//
// R4: fixed-capacity padded buckets (CAP=64 slots/dst, deg ~ Poisson(16),
// P(deg>64) ~ 1e-19) -> NO hist, NO scan. memset cursor -> scatter 8B
// (src,att) payload into bucket -> atomic-free gather (one wave per dst row)
// -> overflow fixup (insurance, expected 0 edges).

#define D 64
#define CAP 64          // slots per dst bucket (512B, line-aligned)
#define OVF_CAP 65536

// ---------------- padded-bucket path ----------------

__global__ void __launch_bounds__(256)
scatter_pad_kernel(const int* __restrict__ dst_idx, const int* __restrict__ src_idx,
                   const float* __restrict__ e_att, int* __restrict__ cursor,
                   long long* __restrict__ payload,
                   int* __restrict__ ovf_count, int* __restrict__ ovf_list, int E) {
    int e = blockIdx.x * blockDim.x + threadIdx.x;
    if (e >= E) return;
    int d = dst_idx[e];
    int p = atomicAdd(&cursor[d], 1);
    if (p < CAP) {
        long long pl = ((long long)__float_as_int(e_att[e]) << 32) |
                       (unsigned int)src_idx[e];
        __builtin_nontemporal_store(pl, payload + (size_t)d * CAP + p);
    } else {
        int oi = atomicAdd(ovf_count, 1);
        if (oi < OVF_CAP) ovf_list[oi] = e;
    }
}

// One wave per dst row. lane = sub*16 + part: sub (0..3) strides bucket slots,
// part (0..15) owns one float4 of the 64-float row.
__global__ void __launch_bounds__(256)
gather_pad_kernel(const float* __restrict__ src_emb,
                  const long long* __restrict__ payload,
                  const int* __restrict__ cursor,
                  float* __restrict__ out, int n_dst) {
    int w = (blockIdx.x * blockDim.x + threadIdx.x) >> 6;
    if (w >= n_dst) return;
    int lane = threadIdx.x & 63;
    int part = lane & 15;
    int sub  = lane >> 4;

    int cnt = cursor[w];
    if (cnt > CAP) cnt = CAP;              // overflow handled by fixup kernel
    const long long* bucket = payload + (size_t)w * CAP;

    float4 acc = make_float4(0.f, 0.f, 0.f, 0.f);
    for (int p = sub; p < cnt; p += 4) {
        long long pl = bucket[p];          // broadcast across the 16 lanes of sub
        int   s = (int)(pl & 0xffffffff);
        float a = __int_as_float((int)(pl >> 32));
        float4 v = ((const float4*)src_emb)[(size_t)s * 16 + part];
        acc.x = fmaf(v.x, a, acc.x);
        acc.y = fmaf(v.y, a, acc.y);
        acc.z = fmaf(v.z, a, acc.z);
        acc.w = fmaf(v.w, a, acc.w);
    }
    acc.x += __shfl_down(acc.x, 32); acc.y += __shfl_down(acc.y, 32);
    acc.z += __shfl_down(acc.z, 32); acc.w += __shfl_down(acc.w, 32);
    acc.x += __shfl_down(acc.x, 16); acc.y += __shfl_down(acc.y, 16);
    acc.z += __shfl_down(acc.z, 16); acc.w += __shfl_down(acc.w, 16);

    if (sub == 0) ((float4*)out)[(size_t)w * 16 + part] = acc;
}

// Insurance: atomically add any edges that overflowed their bucket (expected 0).
// Runs AFTER gather (stream order), so plain atomicAdd on the final values.
__global__ void __launch_bounds__(256)
ovf_fixup_kernel(const float* __restrict__ src_emb, const float* __restrict__ e_att,
                 const int* __restrict__ src_idx, const int* __restrict__ dst_idx,
                 const int* __restrict__ ovf_count, const int* __restrict__ ovf_list,
                 float* __restrict__ out) {
    int cnt = *ovf_count;
    if (cnt > OVF_CAP) cnt = OVF_CAP;
    int n = cnt * 16;
    int nt = gridDim.x * blockDim.x;
    for (int t = blockIdx.x * blockDim.x + threadIdx.x; t < n; t += nt) {
        int e    = ovf_list[t >> 4];
        int part = t & 15;
        int   s = src_idx[e];
        int   d = dst_idx[e];
        float a = e_att[e];
        float4 v = ((const float4*)src_emb)[(size_t)s * 16 + part];
        float* orow = out + (size_t)d * D + part * 4;
        atomicAdd(orow + 0, v.x * a);
        atomicAdd(orow + 1, v.y * a);
        atomicAdd(orow + 2, v.z * a);
        atomicAdd(orow + 3, v.w * a);
    }
}

// ---------------- CSR fallback (ws too small for padded) ----------------

__global__ void __launch_bounds__(256)
hist_kernel(const int* __restrict__ dst_idx, int* __restrict__ counts, int E) {
    int e = blockIdx.x * blockDim.x + threadIdx.x;
    if (e < E) atomicAdd(&counts[dst_idx[e]], 1);
}

__global__ void __launch_bounds__(256)
block_reduce_kernel(const int* __restrict__ counts, int* __restrict__ blocksums, int n) {
    __shared__ int lds[256];
    int i = blockIdx.x * 256 + threadIdx.x;
    lds[threadIdx.x] = (i < n) ? counts[i] : 0;
    __syncthreads();
    for (int s = 128; s > 0; s >>= 1) {
        if (threadIdx.x < s) lds[threadIdx.x] += lds[threadIdx.x + s];
        __syncthreads();
    }
    if (threadIdx.x == 0) blocksums[blockIdx.x] = lds[0];
}

__global__ void __launch_bounds__(256)
scan_blocksums_kernel(int* __restrict__ blocksums, int nb) {
    __shared__ int lds[256];
    int t = threadIdx.x;
    int v = (t < nb) ? blocksums[t] : 0;
    lds[t] = v;
    __syncthreads();
    for (int off = 1; off < 256; off <<= 1) {
        int x = (t >= off) ? lds[t - off] : 0;
        __syncthreads();
        lds[t] += x;
        __syncthreads();
    }
    if (t < nb) blocksums[t] = lds[t] - v;
}

__global__ void __launch_bounds__(256)
scan_final_kernel(const int* __restrict__ counts, const int* __restrict__ blocksums,
                  int* __restrict__ offsets, int* __restrict__ cursor, int n) {
    __shared__ int lds[256];
    int t = threadIdx.x;
    int i = blockIdx.x * 256 + t;
    int v = (i < n) ? counts[i] : 0;
    lds[t] = v;
    __syncthreads();
    for (int off = 1; off < 256; off <<= 1) {
        int x = (t >= off) ? lds[t - off] : 0;
        __syncthreads();
        lds[t] += x;
        __syncthreads();
    }
    int excl = lds[t] - v + blocksums[blockIdx.x];
    if (i < n) {
        offsets[i] = excl; cursor[i] = excl;
        if (i == n - 1) offsets[n] = excl + v;
    }
}

__global__ void __launch_bounds__(256)
scatter_csr_kernel(const int* __restrict__ dst_idx, const int* __restrict__ src_idx,
                   const float* __restrict__ e_att, int* __restrict__ cursor,
                   long long* __restrict__ payload, int E) {
    int e = blockIdx.x * blockDim.x + threadIdx.x;
    if (e < E) {
        int p = atomicAdd(&cursor[dst_idx[e]], 1);
        long long pl = ((long long)__float_as_int(e_att[e]) << 32) |
                       (unsigned int)src_idx[e];
        __builtin_nontemporal_store(pl, payload + p);
    }
}

__global__ void __launch_bounds__(256)
gather_csr_kernel(const float* __restrict__ src_emb,
                  const long long* __restrict__ payload,
                  const int* __restrict__ offsets,
                  float* __restrict__ out, int n_dst) {
    int w = (blockIdx.x * blockDim.x + threadIdx.x) >> 6;
    if (w >= n_dst) return;
    int lane = threadIdx.x & 63;
    int part = lane & 15;
    int sub  = lane >> 4;
    int start = offsets[w];
    int end   = offsets[w + 1];
    float4 acc = make_float4(0.f, 0.f, 0.f, 0.f);
    for (int p = start + sub; p < end; p += 4) {
        long long pl = payload[p];
        int   s = (int)(pl & 0xffffffff);
        float a = __int_as_float((int)(pl >> 32));
        float4 v = ((const float4*)src_emb)[(size_t)s * 16 + part];
        acc.x = fmaf(v.x, a, acc.x);
        acc.y = fmaf(v.y, a, acc.y);
        acc.z = fmaf(v.z, a, acc.z);
        acc.w = fmaf(v.w, a, acc.w);
    }
    acc.x += __shfl_down(acc.x, 32); acc.y += __shfl_down(acc.y, 32);
    acc.z += __shfl_down(acc.z, 32); acc.w += __shfl_down(acc.w, 32);
    acc.x += __shfl_down(acc.x, 16); acc.y += __shfl_down(acc.y, 16);
    acc.z += __shfl_down(acc.z, 16); acc.w += __shfl_down(acc.w, 16);
    if (sub == 0) ((float4*)out)[(size_t)w * 16 + part] = acc;
}

// ---------------- last-resort fallback: pure atomic ----------------
__global__ void __launch_bounds__(256)
atomic_fallback_kernel(const float* __restrict__ src_emb, const float* __restrict__ e_att,
                       const int* __restrict__ src_idx, const int* __restrict__ dst_idx,
                       float* __restrict__ out, int E) {
    int tid  = blockIdx.x * blockDim.x + threadIdx.x;
    int e    = tid >> 4;
    int part = tid & 15;
    if (e >= E) return;
    int   s = src_idx[e];
    int   d = dst_idx[e];
    float a = e_att[e];
    float4 v = ((const float4*)src_emb)[(size_t)s * 16 + part];
    float* orow = out + (size_t)d * D + part * 4;
    atomicAdd(orow + 0, v.x * a);
    atomicAdd(orow + 1, v.y * a);
    atomicAdd(orow + 2, v.z * a);
    atomicAdd(orow + 3, v.w * a);
}

extern "C" void kernel_launch(void* const* d_in, const int* in_sizes, int n_in,
                              void* d_out, int out_size, void* d_ws, size_t ws_size,
                              hipStream_t stream) {
    const float* src_emb = (const float*)d_in[0];
    const float* e_att   = (const float*)d_in[1];
    const int*   src_idx = (const int*)d_in[2];
    const int*   dst_idx = (const int*)d_in[3];
    float*       out     = (float*)d_out;

    const int E     = in_sizes[2];       // 800000
    const int n_dst = out_size / D;      // 50000
    const int eb    = (E + 255) / 256;

    // ---- padded-bucket ws layout (ints):
    // payload[n_dst*CAP*2] | cursor[n_dst] | ovf_count[1] | ovf_list[OVF_CAP]
    size_t pad_ints = (size_t)n_dst * CAP * 2 + n_dst + 1 + OVF_CAP;
    if (ws_size >= pad_ints * sizeof(int)) {
        long long* payload  = (long long*)d_ws;
        int* cursor    = (int*)d_ws + (size_t)n_dst * CAP * 2;
        int* ovf_count = cursor + n_dst;
        int* ovf_list  = ovf_count + 1;

        hipMemsetAsync(cursor, 0, ((size_t)n_dst + 1) * sizeof(int), stream);
        scatter_pad_kernel<<<eb, 256, 0, stream>>>(dst_idx, src_idx, e_att, cursor,
                                                   payload, ovf_count, ovf_list, E);
        gather_pad_kernel<<<(n_dst + 3) / 4, 256, 0, stream>>>(src_emb, payload,
                                                               cursor, out, n_dst);
        ovf_fixup_kernel<<<64, 256, 0, stream>>>(src_emb, e_att, src_idx, dst_idx,
                                                 ovf_count, ovf_list, out);
        return;
    }

    // ---- CSR fallback ws layout (ints):
    // counts[n] | offsets[n+1] | cursor[n] | blocksums[256] | payload[2E] (8B aligned)
    size_t pidx = (size_t)(3 * n_dst + 1 + 256);
    pidx = (pidx + 1) & ~(size_t)1;
    size_t csr_ints = pidx + 2ull * E;
    if (ws_size >= csr_ints * sizeof(int)) {
        int* ws        = (int*)d_ws;
        int* counts    = ws;
        int* offsets   = ws + n_dst;
        int* cursor    = ws + 2 * n_dst + 1;
        int* blocksums = ws + 3 * n_dst + 1;
        long long* payload = (long long*)(ws + pidx);

        hipMemsetAsync(counts, 0, (size_t)n_dst * sizeof(int), stream);
        const int nb = (n_dst + 255) / 256;
        hist_kernel<<<eb, 256, 0, stream>>>(dst_idx, counts, E);
        block_reduce_kernel<<<nb, 256, 0, stream>>>(counts, blocksums, n_dst);
        scan_blocksums_kernel<<<1, 256, 0, stream>>>(blocksums, nb);
        scan_final_kernel<<<nb, 256, 0, stream>>>(counts, blocksums, offsets, cursor, n_dst);
        scatter_csr_kernel<<<eb, 256, 0, stream>>>(dst_idx, src_idx, e_att, cursor,
                                                   payload, E);
        gather_csr_kernel<<<(n_dst + 3) / 4, 256, 0, stream>>>(src_emb, payload,
                                                               offsets, out, n_dst);
        return;
    }

    // ---- last resort: pure atomic
    hipMemsetAsync(d_out, 0, (size_t)out_size * sizeof(float), stream);
    atomic_fallback_kernel<<<(E * 16 + 255) / 256, 256, 0, stream>>>(
        src_emb, e_att, src_idx, dst_idx, out, E);
}